// Round 1
// baseline (624.509 us; speedup 1.0000x reference)
//
#include <hip/hip_runtime.h>
#include <stdint.h>

typedef unsigned short u16;
typedef __attribute__((ext_vector_type(8))) short bf16x8;
typedef __attribute__((ext_vector_type(8))) unsigned short u16x8;
typedef __attribute__((ext_vector_type(4))) float f32x4;

#define AS1 __attribute__((address_space(1)))
#define AS3 __attribute__((address_space(3)))

__device__ __forceinline__ u16 f32_to_bf16(float f) {
  unsigned int u = __builtin_bit_cast(unsigned int, f);
  u += 0x7FFFu + ((u >> 16) & 1u);
  return (u16)(u >> 16);
}
__device__ __forceinline__ float bf16_to_f32(u16 s) {
  return __builtin_bit_cast(float, (unsigned int)s << 16);
}
__device__ __forceinline__ void g2lds16(const void* g, void* l) {
  __builtin_amdgcn_global_load_lds((const AS1 void*)g, (AS3 void*)l, 16, 0, 0);
}

// ---------------- conversions ----------------
__global__ __launch_bounds__(256) void cvt_x(const float* __restrict__ x, u16* __restrict__ xb) {
  size_t i = ((size_t)blockIdx.x * 256 + threadIdx.x) * 8;
  float4 a = *(const float4*)(x + i);
  float4 b = *(const float4*)(x + i + 4);
  u16x8 o;
  o[0]=f32_to_bf16(a.x); o[1]=f32_to_bf16(a.y); o[2]=f32_to_bf16(a.z); o[3]=f32_to_bf16(a.w);
  o[4]=f32_to_bf16(b.x); o[5]=f32_to_bf16(b.y); o[6]=f32_to_bf16(b.z); o[7]=f32_to_bf16(b.w);
  *(u16x8*)(xb + i) = o;
}

// WT[z][n][k] = W_z[k][n], bf16.  4 matrices of 1024x1024.
__global__ void cvt_wt(const float* __restrict__ Wq, const float* __restrict__ Wk,
                       const float* __restrict__ Wv, const float* __restrict__ Wo,
                       u16* __restrict__ WT) {
  __shared__ float tile[32][33];
  const float* W = blockIdx.z==0 ? Wq : blockIdx.z==1 ? Wk : blockIdx.z==2 ? Wv : Wo;
  int n0 = blockIdx.x*32, k0 = blockIdx.y*32;
  int tx = threadIdx.x, ty = threadIdx.y;
  for (int r = ty; r < 32; r += 8)
    tile[r][tx] = W[(size_t)(k0+r)*1024 + n0 + tx];
  __syncthreads();
  u16* out = WT + (size_t)blockIdx.z*1024*1024;
  for (int r = ty; r < 32; r += 8)
    out[(size_t)(n0+r)*1024 + k0 + tx] = f32_to_bf16(tile[tx][r]);
}

// ---------------- 128x128 MFMA GEMM mainloop (m97 structure) ----------------
// C[128x128] += A[gm0..+127][k] * Bt[gn0..+127][k]^T, K=1024, BK=64.
// 256 threads = 4 waves in 2x2; wave tile 64x64 = 4x4 frags of 16x16x32.
__device__ __forceinline__ void gemm_mainloop(const u16* __restrict__ A, const u16* __restrict__ Bt,
                                              size_t gm0, size_t gn0,
                                              u16* As, u16* Bs, f32x4 (&acc)[4][4]) {
  const int t = threadIdx.x;
  const int wave = t >> 6, lane = t & 63;
  const int wr = wave >> 1, wc = wave & 1;
  const int srow = wave*8 + (lane >> 3);   // + it*32 -> tile row being staged
  const int scol = (lane & 7) * 8;         // k-col (8 bf16 = 16B)
  const f32x4 vzero = {0.f, 0.f, 0.f, 0.f};
  #pragma unroll
  for (int mi=0;mi<4;++mi)
    #pragma unroll
    for (int ni=0;ni<4;++ni) acc[mi][ni] = vzero;
  for (int k0 = 0; k0 < 1024; k0 += 64) {
    #pragma unroll
    for (int it = 0; it < 4; ++it) {
      g2lds16(A  + (gm0 + it*32 + srow)*1024 + k0 + scol, (char*)As + it*4096 + wave*1024);
      g2lds16(Bt + (gn0 + it*32 + srow)*1024 + k0 + scol, (char*)Bs + it*4096 + wave*1024);
    }
    __syncthreads();   // drains vmcnt(0) -> LDS tiles ready
    #pragma unroll
    for (int kk = 0; kk < 64; kk += 32) {
      bf16x8 af[4], bfr[4];
      #pragma unroll
      for (int mi=0;mi<4;++mi)
        af[mi] = *(const bf16x8*)&As[(wr*64 + mi*16 + (lane&15))*64 + kk + (lane>>4)*8];
      #pragma unroll
      for (int ni=0;ni<4;++ni)
        bfr[ni] = *(const bf16x8*)&Bs[(wc*64 + ni*16 + (lane&15))*64 + kk + (lane>>4)*8];
      #pragma unroll
      for (int mi=0;mi<4;++mi)
        #pragma unroll
        for (int ni=0;ni<4;++ni)
          acc[mi][ni] = __builtin_amdgcn_mfma_f32_16x16x32_bf16(af[mi], bfr[ni], acc[mi][ni], 0, 0, 0);
    }
    __syncthreads();   // compute done before next stage overwrites LDS
  }
}

// ---------------- QKV projection + bias + feature map ----------------
// out slabs are head-major bf16: [B][H][L][HD]
__global__ __launch_bounds__(256) void qkv_gemm(const u16* __restrict__ xb, const u16* __restrict__ WT,
    const float* __restrict__ bq, const float* __restrict__ bk, const float* __restrict__ bv,
    u16* __restrict__ qf, u16* __restrict__ kf, u16* __restrict__ vv) {
  __shared__ __align__(16) u16 As[128*64];
  __shared__ __align__(16) u16 Bs[128*64];
  const int z = blockIdx.z;
  const u16* Bt = WT + (size_t)z*1024*1024;
  const float* bias = z==0 ? bq : z==1 ? bk : bv;
  u16* outp = z==0 ? qf : z==1 ? kf : vv;
  f32x4 acc[4][4];
  size_t gm0 = (size_t)blockIdx.x*128, gn0 = (size_t)blockIdx.y*128;
  gemm_mainloop(xb, Bt, gm0, gn0, As, Bs, acc);
  const int lane = threadIdx.x & 63, wave = threadIdx.x >> 6;
  const int wr = wave>>1, wc = wave&1;
  const bool feat = (z < 2);
  #pragma unroll
  for (int mi=0;mi<4;++mi) {
    int mbase = (int)gm0 + wr*64 + mi*16 + ((lane>>4)<<2);
    #pragma unroll
    for (int ni=0;ni<4;++ni) {
      int n = (int)gn0 + wc*64 + ni*16 + (lane&15);
      float bias_n = bias[n];
      int h = n >> 6, hd = n & 63;
      #pragma unroll
      for (int r=0;r<4;++r) {
        int m = mbase + r;
        float val = acc[mi][ni][r] + bias_n;
        if (feat) val = val > 0.f ? val + 1.f : __expf(val);   // elu(x)+1
        int b_ = m >> 13, l = m & 8191;
        outp[((size_t)(b_*16 + h)*8192 + l)*64 + hd] = f32_to_bf16(val);
      }
    }
  }
}

// ---------------- kv outer-product partial sums (f32 vector) ----------------
// pkv[p][c][m][d] = sum_{s in chunk c} kf[p][s][d] * v[p][s][m];  pks = sum kf
__global__ __launch_bounds__(256) void kv_partial(const u16* __restrict__ kf, const u16* __restrict__ vv,
                                                  float* __restrict__ pkv, float* __restrict__ pks) {
  __shared__ float lk[32*64];
  __shared__ float lv[32*64];
  int p = blockIdx.x, c = blockIdx.y;
  int t = threadIdx.x;
  int d = t & 63, g = t >> 6;            // g = wave id, owns m-rows g*16..g*16+15
  const u16* kfs = kf + ((size_t)p*8192 + (size_t)c*512)*64;
  const u16* vvs = vv + ((size_t)p*8192 + (size_t)c*512)*64;
  float acc[16];
  #pragma unroll
  for (int j=0;j<16;++j) acc[j] = 0.f;
  float ks = 0.f;
  for (int s0 = 0; s0 < 512; s0 += 32) {
    u16x8 kr = *(const u16x8*)(kfs + (size_t)s0*64 + t*8);
    u16x8 vr = *(const u16x8*)(vvs + (size_t)s0*64 + t*8);
    __syncthreads();
    #pragma unroll
    for (int j=0;j<8;++j) { lk[t*8+j] = bf16_to_f32(kr[j]); lv[t*8+j] = bf16_to_f32(vr[j]); }
    __syncthreads();
    #pragma unroll 4
    for (int s=0;s<32;++s) {
      float kd = lk[s*64 + d];
      ks += kd;
      float4 v0 = *(const float4*)&lv[s*64 + g*16];
      float4 v1 = *(const float4*)&lv[s*64 + g*16 + 4];
      float4 v2 = *(const float4*)&lv[s*64 + g*16 + 8];
      float4 v3 = *(const float4*)&lv[s*64 + g*16 + 12];
      acc[0]+=kd*v0.x; acc[1]+=kd*v0.y; acc[2]+=kd*v0.z; acc[3]+=kd*v0.w;
      acc[4]+=kd*v1.x; acc[5]+=kd*v1.y; acc[6]+=kd*v1.z; acc[7]+=kd*v1.w;
      acc[8]+=kd*v2.x; acc[9]+=kd*v2.y; acc[10]+=kd*v2.z; acc[11]+=kd*v2.w;
      acc[12]+=kd*v3.x; acc[13]+=kd*v3.y; acc[14]+=kd*v3.z; acc[15]+=kd*v3.w;
    }
  }
  float* po = pkv + ((size_t)p*16 + c)*4096;
  #pragma unroll
  for (int j=0;j<16;++j) po[(g*16 + j)*64 + d] = acc[j];
  if (g == 0) pks[(p*16 + c)*64 + d] = ks;
}

// ---------------- reduce partials -> bkv[p][80][64] bf16 ----------------
// rows 0..63 = kv[m][d]; row 64 = ksum[d]; rows 65..79 = 0
__global__ __launch_bounds__(256) void kv_reduce(const float* __restrict__ pkv, const float* __restrict__ pks,
                                                 u16* __restrict__ bkv) {
  int p = blockIdx.x, t = threadIdx.x;
  for (int i = t; i < 4096; i += 256) {
    float s = 0.f;
    for (int c = 0; c < 16; ++c) s += pkv[((size_t)p*16 + c)*4096 + i];
    bkv[(size_t)p*5120 + i] = f32_to_bf16(s);
  }
  if (t < 64) {
    float s = 0.f;
    for (int c = 0; c < 16; ++c) s += pks[(p*16 + c)*64 + t];
    bkv[(size_t)p*5120 + 4096 + t] = f32_to_bf16(s);
  }
  for (int i = 4160 + t; i < 5120; i += 256) bkv[(size_t)p*5120 + i] = 0;
}

// ---------------- y = z * (qf @ kv^T), den fused as extra N column ----------------
// per pair: M=8192 (BM=256/block), N=80 (5 tiles), K=64.  y bf16 [B][L][H][HD]
__global__ __launch_bounds__(256) void y_gemm(const u16* __restrict__ qf, const u16* __restrict__ bkv,
                                              u16* __restrict__ y) {
  __shared__ __align__(16) u16 As[256*64];  // 32KB
  __shared__ __align__(16) u16 Bs[80*64];   // 10KB
  int p = blockIdx.x, rb = blockIdx.y;
  int t = threadIdx.x, wave = t >> 6, lane = t & 63;
  const u16* aslab = qf + ((size_t)p*8192 + (size_t)rb*256)*64;
  for (int i = t*8; i < 5120; i += 2048)
    *(int4*)&Bs[i] = *(const int4*)&bkv[(size_t)p*5120 + i];
  #pragma unroll
  for (int it = 0; it < 8; ++it)
    g2lds16(aslab + it*2048 + t*8, (char*)As + it*4096 + wave*1024);
  __syncthreads();
  const f32x4 vzero = {0.f,0.f,0.f,0.f};
  f32x4 acc[4][5];
  #pragma unroll
  for (int mi=0;mi<4;++mi)
    #pragma unroll
    for (int ni=0;ni<5;++ni) acc[mi][ni] = vzero;
  #pragma unroll
  for (int kk = 0; kk < 64; kk += 32) {
    bf16x8 af[4], bfr[5];
    #pragma unroll
    for (int mi=0;mi<4;++mi)
      af[mi] = *(const bf16x8*)&As[(wave*64 + mi*16 + (lane&15))*64 + kk + (lane>>4)*8];
    #pragma unroll
    for (int ni=0;ni<5;++ni)
      bfr[ni] = *(const bf16x8*)&Bs[(ni*16 + (lane&15))*64 + kk + (lane>>4)*8];
    #pragma unroll
    for (int mi=0;mi<4;++mi)
      #pragma unroll
      for (int ni=0;ni<5;++ni)
        acc[mi][ni] = __builtin_amdgcn_mfma_f32_16x16x32_bf16(af[mi], bfr[ni], acc[mi][ni], 0, 0, 0);
  }
  int b_ = p >> 4, h = p & 15;
  #pragma unroll
  for (int mi=0;mi<4;++mi) {
    #pragma unroll
    for (int r=0;r<4;++r) {
      float den = __shfl(acc[mi][4][r], lane & 48);   // col 64 lives in lanes with (lane&15)==0
      float zf = 1.0f / (den + 1e-6f);
      int l = rb*256 + wave*64 + mi*16 + ((lane>>4)<<2) + r;
      size_t rowbase = ((size_t)(b_*8192 + l)*16 + h)*64;
      #pragma unroll
      for (int ni=0;ni<4;++ni)
        y[rowbase + ni*16 + (lane&15)] = f32_to_bf16(acc[mi][ni][r] * zf);
    }
  }
}

// ---------------- output projection ----------------
__global__ __launch_bounds__(256) void out_gemm(const u16* __restrict__ yb, const u16* __restrict__ WoT,
                                                const float* __restrict__ bo, float* __restrict__ out) {
  __shared__ __align__(16) u16 As[128*64];
  __shared__ __align__(16) u16 Bs[128*64];
  f32x4 acc[4][4];
  size_t gm0 = (size_t)blockIdx.x*128, gn0 = (size_t)blockIdx.y*128;
  gemm_mainloop(yb, WoT, gm0, gn0, As, Bs, acc);
  const int lane = threadIdx.x & 63, wave = threadIdx.x >> 6;
  const int wr = wave>>1, wc = wave&1;
  #pragma unroll
  for (int mi=0;mi<4;++mi) {
    int mbase = (int)gm0 + wr*64 + mi*16 + ((lane>>4)<<2);
    #pragma unroll
    for (int ni=0;ni<4;++ni) {
      int n = (int)gn0 + wc*64 + ni*16 + (lane&15);
      float bias_n = bo[n];
      #pragma unroll
      for (int r=0;r<4;++r) {
        int m = mbase + r;
        out[(size_t)m*1024 + n] = acc[mi][ni][r] + bias_n;
      }
    }
  }
}

extern "C" void kernel_launch(void* const* d_in, const int* in_sizes, int n_in,
                              void* d_out, int out_size, void* d_ws, size_t ws_size,
                              hipStream_t stream) {
  const float* x  = (const float*)d_in[0];
  const float* Wq = (const float*)d_in[1];
  const float* bq = (const float*)d_in[2];
  const float* Wk = (const float*)d_in[3];
  const float* bk = (const float*)d_in[4];
  const float* Wv = (const float*)d_in[5];
  const float* bv = (const float*)d_in[6];
  const float* Wo = (const float*)d_in[7];
  const float* bo = (const float*)d_in[8];
  float* out = (float*)d_out;
  char* ws = (char*)d_ws;

  // ws layout (bytes):
  u16*  xb  = (u16*)(ws);                    // 67,108,864  (reused as y later)
  u16*  WT  = (u16*)(ws + 67108864);         //  8,388,608  (Wq,Wk,Wv,Wo transposed bf16)
  u16*  qf  = (u16*)(ws + 75497472);         // 67,108,864  [B][H][L][HD]
  u16*  kf  = (u16*)(ws + 142606336);        // 67,108,864
  u16*  vv  = (u16*)(ws + 209715200);        // 67,108,864
  float* pkv = (float*)(ws + 276824064);     // 16,777,216  [64][16][64][64]
  float* pks = (float*)(ws + 293601280);     //    262,144
  u16*  bkv = (u16*)(ws + 293863424);        //    655,360  [64][80][64]
  u16*  yb  = xb;                            // alias: x_bf16 dead after qkv_gemm

  cvt_x<<<16384, 256, 0, stream>>>(x, xb);
  cvt_wt<<<dim3(32,32,4), dim3(32,8), 0, stream>>>(Wq, Wk, Wv, Wo, WT);
  qkv_gemm<<<dim3(256,8,3), 256, 0, stream>>>(xb, WT, bq, bk, bv, qf, kf, vv);
  kv_partial<<<dim3(64,16), 256, 0, stream>>>(kf, vv, pkv, pks);
  kv_reduce<<<64, 256, 0, stream>>>(pkv, pks, bkv);
  y_gemm<<<dim3(64,32), 256, 0, stream>>>(qf, bkv, yb);
  out_gemm<<<dim3(256,8), 256, 0, stream>>>(yb, WT + (size_t)3*1048576, bo, out);
}

// Round 3
// 473.258 us; speedup vs baseline: 1.3196x; 1.3196x over previous
//
#include <hip/hip_runtime.h>
#include <stdint.h>

typedef unsigned short u16;
typedef __attribute__((ext_vector_type(8))) short bf16x8;
typedef __attribute__((ext_vector_type(8))) unsigned short u16x8;
typedef __attribute__((ext_vector_type(4))) float f32x4;

#define AS1 __attribute__((address_space(1)))
#define AS3 __attribute__((address_space(3)))

__device__ __forceinline__ u16 f32_to_bf16(float f) {
  unsigned int u = __builtin_bit_cast(unsigned int, f);
  u += 0x7FFFu + ((u >> 16) & 1u);
  return (u16)(u >> 16);
}
__device__ __forceinline__ float bf16_to_f32(u16 s) {
  return __builtin_bit_cast(float, (unsigned int)s << 16);
}
__device__ __forceinline__ void g2lds16(const void* g, void* l) {
  __builtin_amdgcn_global_load_lds((const AS1 void*)g, (AS3 void*)l, 16, 0, 0);
}

// ---------------- conversions ----------------
__global__ __launch_bounds__(256) void cvt_x(const float* __restrict__ x, u16* __restrict__ xb) {
  size_t i = ((size_t)blockIdx.x * 256 + threadIdx.x) * 8;
  float4 a = *(const float4*)(x + i);
  float4 b = *(const float4*)(x + i + 4);
  u16x8 o;
  o[0]=f32_to_bf16(a.x); o[1]=f32_to_bf16(a.y); o[2]=f32_to_bf16(a.z); o[3]=f32_to_bf16(a.w);
  o[4]=f32_to_bf16(b.x); o[5]=f32_to_bf16(b.y); o[6]=f32_to_bf16(b.z); o[7]=f32_to_bf16(b.w);
  *(u16x8*)(xb + i) = o;
}

// WT[z][n][k] = W_z[k][n], bf16.  4 matrices of 1024x1024.
__global__ void cvt_wt(const float* __restrict__ Wq, const float* __restrict__ Wk,
                       const float* __restrict__ Wv, const float* __restrict__ Wo,
                       u16* __restrict__ WT) {
  __shared__ float tile[32][33];
  const float* W = blockIdx.z==0 ? Wq : blockIdx.z==1 ? Wk : blockIdx.z==2 ? Wv : Wo;
  int n0 = blockIdx.x*32, k0 = blockIdx.y*32;
  int tx = threadIdx.x, ty = threadIdx.y;
  for (int r = ty; r < 32; r += 8)
    tile[r][tx] = W[(size_t)(k0+r)*1024 + n0 + tx];
  __syncthreads();
  u16* out = WT + (size_t)blockIdx.z*1024*1024;
  for (int r = ty; r < 32; r += 8)
    out[(size_t)(n0+r)*1024 + k0 + tx] = f32_to_bf16(tile[tx][r]);
}

// ================= 256x256 8-phase GEMM (T1+T2+T3+T4+T5) =================
// 512 threads = 8 waves (2M x 4N). BK=64, K=1024 (16 tiles). LDS 128KB:
//   A[buf] 32KB at buf*32768, B[buf] 32KB at 65536+buf*32768; halves 16KB.
// Swizzle: LDS[row][slot] holds G[row][slot ^ (row&7)] (slot = 16B unit).
// Phase p=(mh,nh) computes quadrant (mh*128 rows, nh*128 cols), reads only
// A-half mh, B-half nh. Prefetch of tile kt+1 during kt: A0@p0,B0@p1,B1@p2,A1@p3.
// Waits: vmcnt(4) before phases 0,1,3 barrier => needed half always landed,
// >=4 loads always in flight (T4: never drain to 0 in main loop).
// MODE 0: qkv epilogue (bias, elu+1 for z<2, head-major bf16 out slabs)
// MODE 1: f32 row-major out = acc + bo
template<int MODE>
__global__ __launch_bounds__(512) void gemm8(const u16* __restrict__ A, const u16* __restrict__ WT,
    const float* __restrict__ bq, const float* __restrict__ bk, const float* __restrict__ bv,
    u16* __restrict__ qf, u16* __restrict__ kf, u16* __restrict__ vv,
    float* __restrict__ fout) {
  extern __shared__ u16 lds[];
  const int z = (MODE==0) ? blockIdx.y : 3;
  const u16* Bt = WT + (size_t)z*1048576;
  int bid = blockIdx.x;
  int swz = (bid & 7)*64 + (bid >> 3);        // 512 blocks, bijective XCD swizzle
  int rb = swz >> 2, cb = swz & 3;
  const int gm0 = rb*256, gn0 = cb*256;
  const int t = threadIdx.x, w = t>>6, l = t&63;
  const int wm = w>>2, wn = w&3;
  const int lrow = l & 15, lks = l >> 4;
  const int csw = (l&7) ^ (l>>3);             // pre-swizzled source slot
  const u16* aBase = A  + (size_t)(gm0 + w*8 + (l>>3))*1024 + csw*8;
  const u16* bBase = Bt + (size_t)(gn0 + w*8 + (l>>3))*1024 + csw*8;

  f32x4 acc[2][2][4][2];
  const f32x4 vzero = {0.f,0.f,0.f,0.f};
  #pragma unroll
  for (int a0=0;a0<2;++a0)
    #pragma unroll
    for (int b0=0;b0<2;++b0)
      #pragma unroll
      for (int c0=0;c0<4;++c0)
        #pragma unroll
        for (int d0=0;d0<2;++d0) acc[a0][b0][c0][d0] = vzero;

  // prologue: stage full tile 0 into buf0
  #pragma unroll
  for (int half=0; half<2; ++half)
    #pragma unroll
    for (int j=0;j<2;++j) {
      g2lds16(aBase + (half*128 + j*64)*1024, (char*)lds + half*16384 + j*8192 + w*1024);
      g2lds16(bBase + (half*128 + j*64)*1024, (char*)lds + 65536 + half*16384 + j*8192 + w*1024);
    }
  asm volatile("s_waitcnt vmcnt(0)" ::: "memory");
  __builtin_amdgcn_s_barrier();
  asm volatile("" ::: "memory");

  for (int kt = 0; kt < 16; ++kt) {
    const int buf = kt & 1;
    const char* Ab = (const char*)lds + buf*32768;
    const char* Bb = (const char*)lds + 65536 + buf*32768;
    char* An = (char*)lds + (buf^1)*32768;
    char* Bn = (char*)lds + 65536 + (buf^1)*32768;
    const u16* aSrc = aBase + (size_t)(kt+1)*64;
    const u16* bSrc = bBase + (size_t)(kt+1)*64;
    const bool pf = (kt < 15);
    #pragma unroll
    for (int ph = 0; ph < 4; ++ph) {
      const int mh = ph >> 1, nh = ph & 1;
      bf16x8 af[4][2], bfr[2][2];
      #pragma unroll
      for (int mi=0;mi<4;++mi) {
        int row = mh*128 + wm*64 + mi*16 + lrow;
        #pragma unroll
        for (int kx=0;kx<2;++kx) {
          int slot = kx*4 + lks;
          af[mi][kx] = *(const bf16x8*)(Ab + row*128 + ((slot ^ (row&7))<<4));
        }
      }
      #pragma unroll
      for (int ni=0;ni<2;++ni) {
        int row = nh*128 + wn*32 + ni*16 + lrow;
        #pragma unroll
        for (int kx=0;kx<2;++kx) {
          int slot = kx*4 + lks;
          bfr[ni][kx] = *(const bf16x8*)(Bb + row*128 + ((slot ^ (row&7))<<4));
        }
      }
      if (pf) {
        // stage one half-tile of tile kt+1: p0->A0, p1->B0, p2->B1, p3->A1
        const u16* s; char* d;
        if (ph==0)      { s = aSrc;            d = An;         }
        else if (ph==1) { s = bSrc;            d = Bn;         }
        else if (ph==2) { s = bSrc + 128*1024; d = Bn + 16384; }
        else            { s = aSrc + 128*1024; d = An + 16384; }
        #pragma unroll
        for (int j=0;j<2;++j)
          g2lds16(s + j*64*1024, d + j*8192 + w*1024);
        if (ph != 2) asm volatile("s_waitcnt vmcnt(4)" ::: "memory");
      } else {
        if (ph == 0)      asm volatile("s_waitcnt vmcnt(2)" ::: "memory");
        else if (ph == 1) asm volatile("s_waitcnt vmcnt(0)" ::: "memory");
      }
      __builtin_amdgcn_s_barrier();
      asm volatile("" ::: "memory");
      __builtin_amdgcn_s_setprio(1);
      #pragma unroll
      for (int mi=0;mi<4;++mi)
        #pragma unroll
        for (int ni=0;ni<2;++ni) {
          acc[mh][nh][mi][ni] = __builtin_amdgcn_mfma_f32_16x16x32_bf16(af[mi][0], bfr[ni][0], acc[mh][nh][mi][ni], 0,0,0);
          acc[mh][nh][mi][ni] = __builtin_amdgcn_mfma_f32_16x16x32_bf16(af[mi][1], bfr[ni][1], acc[mh][nh][mi][ni], 0,0,0);
        }
      __builtin_amdgcn_s_setprio(0);
      __builtin_amdgcn_s_barrier();
      asm volatile("" ::: "memory");
    }
  }

  // epilogue
  if (MODE == 0) {
    const float* bias = z==0 ? bq : (z==1 ? bk : bv);
    u16* outp = z==0 ? qf : (z==1 ? kf : vv);
    const bool feat = (z < 2);
    #pragma unroll
    for (int mh=0;mh<2;++mh)
      #pragma unroll
      for (int nh=0;nh<2;++nh)
        #pragma unroll
        for (int mi=0;mi<4;++mi)
          #pragma unroll
          for (int ni=0;ni<2;++ni) {
            int n = gn0 + nh*128 + wn*32 + ni*16 + lrow;
            float bn = bias[n];
            int h = n>>6, hd = n&63;
            int mbase = gm0 + mh*128 + wm*64 + mi*16 + (lks<<2);
            #pragma unroll
            for (int r=0;r<4;++r) {
              int m = mbase + r;
              float val = acc[mh][nh][mi][ni][r] + bn;
              if (feat) val = val>0.f ? val+1.f : __expf(val);
              outp[((size_t)((m>>13)*16 + h)*8192 + (m&8191))*64 + hd] = f32_to_bf16(val);
            }
          }
  } else {
    #pragma unroll
    for (int mh=0;mh<2;++mh)
      #pragma unroll
      for (int nh=0;nh<2;++nh)
        #pragma unroll
        for (int mi=0;mi<4;++mi)
          #pragma unroll
          for (int ni=0;ni<2;++ni) {
            int n = gn0 + nh*128 + wn*32 + ni*16 + lrow;
            float bn = bq[n];   // MODE1: bq carries bo
            int mbase = gm0 + mh*128 + wm*64 + mi*16 + (lks<<2);
            #pragma unroll
            for (int r=0;r<4;++r) {
              int m = mbase + r;
              fout[(size_t)m*1024 + n] = acc[mh][nh][mi][ni][r] + bn;
            }
          }
  }
}

// ---------------- kv outer-product partial sums (f32 vector) ----------------
__global__ __launch_bounds__(256) void kv_partial(const u16* __restrict__ kf, const u16* __restrict__ vv,
                                                  float* __restrict__ pkv, float* __restrict__ pks) {
  __shared__ float lk[32*64];
  __shared__ float lv[32*64];
  int p = blockIdx.x, c = blockIdx.y;
  int t = threadIdx.x;
  int d = t & 63, g = t >> 6;
  const u16* kfs = kf + ((size_t)p*8192 + (size_t)c*512)*64;
  const u16* vvs = vv + ((size_t)p*8192 + (size_t)c*512)*64;
  float acc[16];
  #pragma unroll
  for (int j=0;j<16;++j) acc[j] = 0.f;
  float ks = 0.f;
  for (int s0 = 0; s0 < 512; s0 += 32) {
    u16x8 kr = *(const u16x8*)(kfs + (size_t)s0*64 + t*8);
    u16x8 vr = *(const u16x8*)(vvs + (size_t)s0*64 + t*8);
    __syncthreads();
    #pragma unroll
    for (int j=0;j<8;++j) { lk[t*8+j] = bf16_to_f32(kr[j]); lv[t*8+j] = bf16_to_f32(vr[j]); }
    __syncthreads();
    #pragma unroll 4
    for (int s=0;s<32;++s) {
      float kd = lk[s*64 + d];
      ks += kd;
      float4 v0 = *(const float4*)&lv[s*64 + g*16];
      float4 v1 = *(const float4*)&lv[s*64 + g*16 + 4];
      float4 v2 = *(const float4*)&lv[s*64 + g*16 + 8];
      float4 v3 = *(const float4*)&lv[s*64 + g*16 + 12];
      acc[0]+=kd*v0.x; acc[1]+=kd*v0.y; acc[2]+=kd*v0.z; acc[3]+=kd*v0.w;
      acc[4]+=kd*v1.x; acc[5]+=kd*v1.y; acc[6]+=kd*v1.z; acc[7]+=kd*v1.w;
      acc[8]+=kd*v2.x; acc[9]+=kd*v2.y; acc[10]+=kd*v2.z; acc[11]+=kd*v2.w;
      acc[12]+=kd*v3.x; acc[13]+=kd*v3.y; acc[14]+=kd*v3.z; acc[15]+=kd*v3.w;
    }
  }
  float* po = pkv + ((size_t)p*16 + c)*4096;
  #pragma unroll
  for (int j=0;j<16;++j) po[(g*16 + j)*64 + d] = acc[j];
  if (g == 0) pks[(p*16 + c)*64 + d] = ks;
}

__global__ __launch_bounds__(256) void kv_reduce(const float* __restrict__ pkv, const float* __restrict__ pks,
                                                 u16* __restrict__ bkv) {
  int p = blockIdx.x, t = threadIdx.x;
  for (int i = t; i < 4096; i += 256) {
    float s = 0.f;
    for (int c = 0; c < 16; ++c) s += pkv[((size_t)p*16 + c)*4096 + i];
    bkv[(size_t)p*5120 + i] = f32_to_bf16(s);
  }
  if (t < 64) {
    float s = 0.f;
    for (int c = 0; c < 16; ++c) s += pks[(p*16 + c)*64 + t];
    bkv[(size_t)p*5120 + 4096 + t] = f32_to_bf16(s);
  }
  for (int i = 4160 + t; i < 5120; i += 256) bkv[(size_t)p*5120 + i] = 0;
}

// ---------------- y = z * (qf @ kv^T), den fused as extra N column ----------------
__global__ __launch_bounds__(256) void y_gemm(const u16* __restrict__ qf, const u16* __restrict__ bkv,
                                              u16* __restrict__ y) {
  __shared__ __align__(16) u16 As[256*64];
  __shared__ __align__(16) u16 Bs[80*64];
  int p = blockIdx.x, rb = blockIdx.y;
  int t = threadIdx.x, wave = t >> 6, lane = t & 63;
  const u16* aslab = qf + ((size_t)p*8192 + (size_t)rb*256)*64;
  for (int i = t*8; i < 5120; i += 2048)
    *(int4*)&Bs[i] = *(const int4*)&bkv[(size_t)p*5120 + i];
  #pragma unroll
  for (int it = 0; it < 8; ++it)
    g2lds16(aslab + it*2048 + t*8, (char*)As + it*4096 + wave*1024);
  __syncthreads();
  const f32x4 vzero = {0.f,0.f,0.f,0.f};
  f32x4 acc[4][5];
  #pragma unroll
  for (int mi=0;mi<4;++mi)
    #pragma unroll
    for (int ni=0;ni<5;++ni) acc[mi][ni] = vzero;
  #pragma unroll
  for (int kk = 0; kk < 64; kk += 32) {
    bf16x8 af[4], bfr[5];
    #pragma unroll
    for (int mi=0;mi<4;++mi)
      af[mi] = *(const bf16x8*)&As[(wave*64 + mi*16 + (lane&15))*64 + kk + (lane>>4)*8];
    #pragma unroll
    for (int ni=0;ni<5;++ni)
      bfr[ni] = *(const bf16x8*)&Bs[(ni*16 + (lane&15))*64 + kk + (lane>>4)*8];
    #pragma unroll
    for (int mi=0;mi<4;++mi)
      #pragma unroll
      for (int ni=0;ni<5;++ni)
        acc[mi][ni] = __builtin_amdgcn_mfma_f32_16x16x32_bf16(af[mi], bfr[ni], acc[mi][ni], 0, 0, 0);
  }
  int b_ = p >> 4, h = p & 15;
  #pragma unroll
  for (int mi=0;mi<4;++mi) {
    #pragma unroll
    for (int r=0;r<4;++r) {
      float den = __shfl(acc[mi][4][r], lane & 48);
      float zf = 1.0f / (den + 1e-6f);
      int lq = rb*256 + wave*64 + mi*16 + ((lane>>4)<<2) + r;
      size_t rowbase = ((size_t)(b_*8192 + lq)*16 + h)*64;
      #pragma unroll
      for (int ni=0;ni<4;++ni)
        y[rowbase + ni*16 + (lane&15)] = f32_to_bf16(acc[mi][ni][r] * zf);
    }
  }
}

extern "C" void kernel_launch(void* const* d_in, const int* in_sizes, int n_in,
                              void* d_out, int out_size, void* d_ws, size_t ws_size,
                              hipStream_t stream) {
  const float* x  = (const float*)d_in[0];
  const float* Wq = (const float*)d_in[1];
  const float* bq = (const float*)d_in[2];
  const float* Wk = (const float*)d_in[3];
  const float* bk = (const float*)d_in[4];
  const float* Wv = (const float*)d_in[5];
  const float* bv = (const float*)d_in[6];
  const float* Wo = (const float*)d_in[7];
  const float* bo = (const float*)d_in[8];
  float* out = (float*)d_out;
  char* ws = (char*)d_ws;

  u16*  xb  = (u16*)(ws);                    // 64MB (reused as y later)
  u16*  WT  = (u16*)(ws + 67108864);         //  8MB
  u16*  qf  = (u16*)(ws + 75497472);         // 64MB [B][H][L][HD]
  u16*  kf  = (u16*)(ws + 142606336);        // 64MB
  u16*  vv  = (u16*)(ws + 209715200);        // 64MB
  float* pkv = (float*)(ws + 276824064);     // 16MB
  float* pks = (float*)(ws + 293601280);     // 256KB
  u16*  bkv = (u16*)(ws + 293863424);        // 640KB
  u16*  yb  = xb;

  auto kq = gemm8<0>; auto ko = gemm8<1>;
  hipFuncSetAttribute((const void*)kq, hipFuncAttributeMaxDynamicSharedMemorySize, 131072);
  hipFuncSetAttribute((const void*)ko, hipFuncAttributeMaxDynamicSharedMemorySize, 131072);

  cvt_x<<<16384, 256, 0, stream>>>(x, xb);
  cvt_wt<<<dim3(32,32,4), dim3(32,8), 0, stream>>>(Wq, Wk, Wv, Wo, WT);
  gemm8<0><<<dim3(512,3), 512, 131072, stream>>>(xb, WT, bq, bk, bv, qf, kf, vv, nullptr);
  kv_partial<<<dim3(64,16), 256, 0, stream>>>(kf, vv, pkv, pks);
  kv_reduce<<<64, 256, 0, stream>>>(pkv, pks, bkv);
  y_gemm<<<dim3(64,32), 256, 0, stream>>>(qf, bkv, yb);
  gemm8<1><<<dim3(512,1), 512, 131072, stream>>>(yb, WT, bo, nullptr, nullptr, nullptr, nullptr, nullptr, out);
}

// Round 7
// 441.394 us; speedup vs baseline: 1.4149x; 1.0722x over previous
//
#include <hip/hip_runtime.h>
#include <stdint.h>

typedef unsigned short u16;
typedef __attribute__((ext_vector_type(8))) short bf16x8;
typedef __attribute__((ext_vector_type(8))) unsigned short u16x8;
typedef __attribute__((ext_vector_type(4))) float f32x4;

#define AS1 __attribute__((address_space(1)))
#define AS3 __attribute__((address_space(3)))

__device__ __forceinline__ u16 f32_to_bf16(float f) {
  unsigned int u = __builtin_bit_cast(unsigned int, f);
  u += 0x7FFFu + ((u >> 16) & 1u);
  return (u16)(u >> 16);
}
__device__ __forceinline__ float bf16_to_f32(u16 s) {
  return __builtin_bit_cast(float, (unsigned int)s << 16);
}
__device__ __forceinline__ void g2lds16(const void* g, void* l) {
  __builtin_amdgcn_global_load_lds((const AS1 void*)g, (AS3 void*)l, 16, 0, 0);
}

// ---------------- conversions ----------------
__global__ __launch_bounds__(256) void cvt_x(const float* __restrict__ x, u16* __restrict__ xb) {
  size_t i = ((size_t)blockIdx.x * 256 + threadIdx.x) * 8;
  float4 a = *(const float4*)(x + i);
  float4 b = *(const float4*)(x + i + 4);
  u16x8 o;
  o[0]=f32_to_bf16(a.x); o[1]=f32_to_bf16(a.y); o[2]=f32_to_bf16(a.z); o[3]=f32_to_bf16(a.w);
  o[4]=f32_to_bf16(b.x); o[5]=f32_to_bf16(b.y); o[6]=f32_to_bf16(b.z); o[7]=f32_to_bf16(b.w);
  *(u16x8*)(xb + i) = o;
}

// WT[z][n][k] = W_z[k][n], bf16.  4 matrices of 1024x1024.
__global__ void cvt_wt(const float* __restrict__ Wq, const float* __restrict__ Wk,
                       const float* __restrict__ Wv, const float* __restrict__ Wo,
                       u16* __restrict__ WT) {
  __shared__ float tile[32][33];
  const float* W = blockIdx.z==0 ? Wq : blockIdx.z==1 ? Wk : blockIdx.z==2 ? Wv : Wo;
  int n0 = blockIdx.x*32, k0 = blockIdx.y*32;
  int tx = threadIdx.x, ty = threadIdx.y;
  for (int r = ty; r < 32; r += 8)
    tile[r][tx] = W[(size_t)(k0+r)*1024 + n0 + tx];
  __syncthreads();
  u16* out = WT + (size_t)blockIdx.z*1024*1024;
  for (int r = ty; r < 32; r += 8)
    out[(size_t)(n0+r)*1024 + k0 + tx] = f32_to_bf16(tile[tx][r]);
}

// ================= 256x256 8-phase GEMM (T1+T2+T3+T4+T5) =================
// 512 threads = 8 waves (2M x 4N). BK=64, K=1024 (16 tiles). LDS 128KB.
// Swizzle: LDS[row][slot] holds G[row][slot ^ (row&7)] (slot = 16B unit).
// Phase order (mh,nh): (0,0)->(0,1)->(1,1)->(1,0); fragments persist in regs:
//   ph0 reads af(mh0)+b0, ph1 reads b1, ph2 reads af(mh1), ph3 reads nothing.
//   => 24 ds_read_b128 per K-tile (vs 48 naive) - LDS BW no longer binding.
// Prefetch kt+1: A0@p0, B0@p1, B1@p2, A1@p3; vmcnt(4) at p0,p1,p3 (never 0).
template<int MODE>
__global__ __launch_bounds__(512) void gemm8(const u16* __restrict__ A, const u16* __restrict__ WT,
    const float* __restrict__ bq, const float* __restrict__ bk, const float* __restrict__ bv,
    u16* __restrict__ qf, u16* __restrict__ kf, u16* __restrict__ vv,
    float* __restrict__ fout) {
  extern __shared__ u16 lds[];
  const int z = (MODE==0) ? blockIdx.y : 3;
  const u16* Bt = WT + (size_t)z*1048576;
  int bid = blockIdx.x;
  int swz = (bid & 7)*64 + (bid >> 3);        // 512 blocks, bijective XCD swizzle
  int rb = swz >> 2, cb = swz & 3;
  const int gm0 = rb*256, gn0 = cb*256;
  const int t = threadIdx.x, w = t>>6, l = t&63;
  const int wm = w>>2, wn = w&3;
  const int lrow = l & 15, lks = l >> 4;
  const int csw = (l&7) ^ (l>>3);             // pre-swizzled source slot
  const u16* aBase = A  + (size_t)(gm0 + w*8 + (l>>3))*1024 + csw*8;
  const u16* bBase = Bt + (size_t)(gn0 + w*8 + (l>>3))*1024 + csw*8;

  f32x4 acc[2][2][4][2];
  const f32x4 vzero = {0.f,0.f,0.f,0.f};
  #pragma unroll
  for (int a0=0;a0<2;++a0)
    #pragma unroll
    for (int b0i=0;b0i<2;++b0i)
      #pragma unroll
      for (int c0=0;c0<4;++c0)
        #pragma unroll
        for (int d0=0;d0<2;++d0) acc[a0][b0i][c0][d0] = vzero;

  // prologue: stage full tile 0 into buf0
  #pragma unroll
  for (int half=0; half<2; ++half)
    #pragma unroll
    for (int j=0;j<2;++j) {
      g2lds16(aBase + (half*128 + j*64)*1024, (char*)lds + half*16384 + j*8192 + w*1024);
      g2lds16(bBase + (half*128 + j*64)*1024, (char*)lds + 65536 + half*16384 + j*8192 + w*1024);
    }
  asm volatile("s_waitcnt vmcnt(0)" ::: "memory");
  __builtin_amdgcn_s_barrier();
  asm volatile("" ::: "memory");

  for (int kt = 0; kt < 16; ++kt) {
    const int buf = kt & 1;
    const char* Ab = (const char*)lds + buf*32768;
    const char* Bb = (const char*)lds + 65536 + buf*32768;
    char* An = (char*)lds + (buf^1)*32768;
    char* Bn = (char*)lds + 65536 + (buf^1)*32768;
    const u16* aSrc = aBase + (size_t)(kt+1)*64;
    const u16* bSrc = bBase + (size_t)(kt+1)*64;
    const bool pf = (kt < 15);

    bf16x8 af[4][2];   // current mh's A fragments
    bf16x8 b0[2][2];   // nh=0 B fragments (persist ph0->ph3)
    bf16x8 b1[2][2];   // nh=1 B fragments (persist ph1->ph2)

    #define LD_A(MH)                                                         \
      _Pragma("unroll")                                                      \
      for (int mi=0;mi<4;++mi) {                                             \
        int row = (MH)*128 + wm*64 + mi*16 + lrow;                           \
        _Pragma("unroll")                                                    \
        for (int kx=0;kx<2;++kx)                                             \
          af[mi][kx] = *(const bf16x8*)(Ab + row*128 + (((kx*4+lks) ^ (row&7))<<4)); \
      }
    #define LD_B(DST,NH)                                                     \
      _Pragma("unroll")                                                      \
      for (int ni=0;ni<2;++ni) {                                             \
        int row = (NH)*128 + wn*32 + ni*16 + lrow;                           \
        _Pragma("unroll")                                                    \
        for (int kx=0;kx<2;++kx)                                             \
          DST[ni][kx] = *(const bf16x8*)(Bb + row*128 + (((kx*4+lks) ^ (row&7))<<4)); \
      }
    #define MFMA16(MH,NH,BF)                                                 \
      __builtin_amdgcn_s_setprio(1);                                         \
      _Pragma("unroll")                                                      \
      for (int mi=0;mi<4;++mi)                                               \
        _Pragma("unroll")                                                    \
        for (int ni=0;ni<2;++ni) {                                           \
          acc[MH][NH][mi][ni] = __builtin_amdgcn_mfma_f32_16x16x32_bf16(af[mi][0], BF[ni][0], acc[MH][NH][mi][ni], 0,0,0); \
          acc[MH][NH][mi][ni] = __builtin_amdgcn_mfma_f32_16x16x32_bf16(af[mi][1], BF[ni][1], acc[MH][NH][mi][ni], 0,0,0); \
        }                                                                    \
      __builtin_amdgcn_s_setprio(0);                                         \
      __builtin_amdgcn_s_barrier();                                          \
      asm volatile("" ::: "memory");

    // ---- phase 0: (mh0, nh0) ----
    LD_A(0); LD_B(b0, 0);
    if (pf) { g2lds16(aSrc, An + w*1024); g2lds16(aSrc + 64*1024, An + 8192 + w*1024); }
    if (pf) { asm volatile("s_waitcnt vmcnt(4)" ::: "memory"); }
    else    { asm volatile("s_waitcnt vmcnt(2)" ::: "memory"); }
    __builtin_amdgcn_s_barrier();
    asm volatile("" ::: "memory");
    MFMA16(0, 0, b0);

    // ---- phase 1: (mh0, nh1) ----
    LD_B(b1, 1);
    if (pf) { g2lds16(bSrc, Bn + w*1024); g2lds16(bSrc + 64*1024, Bn + 8192 + w*1024); }
    if (pf) { asm volatile("s_waitcnt vmcnt(4)" ::: "memory"); }
    else    { asm volatile("s_waitcnt vmcnt(0)" ::: "memory"); }
    __builtin_amdgcn_s_barrier();
    asm volatile("" ::: "memory");
    MFMA16(0, 1, b1);

    // ---- phase 2: (mh1, nh1) ----
    LD_A(1);
    if (pf) { g2lds16(bSrc + 128*1024, Bn + 16384 + w*1024); g2lds16(bSrc + 192*1024, Bn + 24576 + w*1024); }
    __builtin_amdgcn_s_barrier();
    asm volatile("" ::: "memory");
    MFMA16(1, 1, b1);

    // ---- phase 3: (mh1, nh0) ----
    if (pf) { g2lds16(aSrc + 128*1024, An + 16384 + w*1024); g2lds16(aSrc + 192*1024, An + 24576 + w*1024); }
    if (pf) { asm volatile("s_waitcnt vmcnt(4)" ::: "memory"); }
    __builtin_amdgcn_s_barrier();
    asm volatile("" ::: "memory");
    MFMA16(1, 0, b0);

    #undef LD_A
    #undef LD_B
    #undef MFMA16
  }

  // epilogue
  if (MODE == 0) {
    const float* bias = z==0 ? bq : (z==1 ? bk : bv);
    u16* outp = z==0 ? qf : (z==1 ? kf : vv);
    const bool feat = (z < 2);
    #pragma unroll
    for (int mh=0;mh<2;++mh)
      #pragma unroll
      for (int nh=0;nh<2;++nh)
        #pragma unroll
        for (int mi=0;mi<4;++mi)
          #pragma unroll
          for (int ni=0;ni<2;++ni) {
            int n = gn0 + nh*128 + wn*32 + ni*16 + lrow;
            float bn = bias[n];
            int h = n>>6, hd = n&63;
            int mbase = gm0 + mh*128 + wm*64 + mi*16 + (lks<<2);
            #pragma unroll
            for (int r=0;r<4;++r) {
              int m = mbase + r;
              float val = acc[mh][nh][mi][ni][r] + bn;
              if (feat) val = val>0.f ? val+1.f : __expf(val);
              outp[((size_t)((m>>13)*16 + h)*8192 + (m&8191))*64 + hd] = f32_to_bf16(val);
            }
          }
  } else {
    #pragma unroll
    for (int mh=0;mh<2;++mh)
      #pragma unroll
      for (int nh=0;nh<2;++nh)
        #pragma unroll
        for (int mi=0;mi<4;++mi)
          #pragma unroll
          for (int ni=0;ni<2;++ni) {
            int n = gn0 + nh*128 + wn*32 + ni*16 + lrow;
            float bn = bq[n];   // MODE1: bq carries bo
            int mbase = gm0 + mh*128 + wm*64 + mi*16 + (lks<<2);
            #pragma unroll
            for (int r=0;r<4;++r) {
              int m = mbase + r;
              fout[(size_t)m*1024 + n] = acc[mh][nh][mi][ni][r] + bn;
            }
          }
  }
}

// ---------------- kv outer-product partial sums (f32 vector) ----------------
__global__ __launch_bounds__(256) void kv_partial(const u16* __restrict__ kf, const u16* __restrict__ vv,
                                                  float* __restrict__ pkv, float* __restrict__ pks) {
  __shared__ float lk[32*64];
  __shared__ float lv[32*64];
  int p = blockIdx.x, c = blockIdx.y;
  int t = threadIdx.x;
  int d = t & 63, g = t >> 6;
  const u16* kfs = kf + ((size_t)p*8192 + (size_t)c*512)*64;
  const u16* vvs = vv + ((size_t)p*8192 + (size_t)c*512)*64;
  float acc[16];
  #pragma unroll
  for (int j=0;j<16;++j) acc[j] = 0.f;
  float ks = 0.f;
  for (int s0 = 0; s0 < 512; s0 += 32) {
    u16x8 kr = *(const u16x8*)(kfs + (size_t)s0*64 + t*8);
    u16x8 vr = *(const u16x8*)(vvs + (size_t)s0*64 + t*8);
    __syncthreads();
    #pragma unroll
    for (int j=0;j<8;++j) { lk[t*8+j] = bf16_to_f32(kr[j]); lv[t*8+j] = bf16_to_f32(vr[j]); }
    __syncthreads();
    #pragma unroll 4
    for (int s=0;s<32;++s) {
      float kd = lk[s*64 + d];
      ks += kd;
      float4 v0 = *(const float4*)&lv[s*64 + g*16];
      float4 v1 = *(const float4*)&lv[s*64 + g*16 + 4];
      float4 v2 = *(const float4*)&lv[s*64 + g*16 + 8];
      float4 v3 = *(const float4*)&lv[s*64 + g*16 + 12];
      acc[0]+=kd*v0.x; acc[1]+=kd*v0.y; acc[2]+=kd*v0.z; acc[3]+=kd*v0.w;
      acc[4]+=kd*v1.x; acc[5]+=kd*v1.y; acc[6]+=kd*v1.z; acc[7]+=kd*v1.w;
      acc[8]+=kd*v2.x; acc[9]+=kd*v2.y; acc[10]+=kd*v2.z; acc[11]+=kd*v2.w;
      acc[12]+=kd*v3.x; acc[13]+=kd*v3.y; acc[14]+=kd*v3.z; acc[15]+=kd*v3.w;
    }
  }
  float* po = pkv + ((size_t)p*16 + c)*4096;
  #pragma unroll
  for (int j=0;j<16;++j) po[(g*16 + j)*64 + d] = acc[j];
  if (g == 0) pks[(p*16 + c)*64 + d] = ks;
}

__global__ __launch_bounds__(256) void kv_reduce(const float* __restrict__ pkv, const float* __restrict__ pks,
                                                 u16* __restrict__ bkv) {
  int p = blockIdx.x, t = threadIdx.x;
  for (int i = t; i < 4096; i += 256) {
    float s = 0.f;
    for (int c = 0; c < 16; ++c) s += pkv[((size_t)p*16 + c)*4096 + i];
    bkv[(size_t)p*5120 + i] = f32_to_bf16(s);
  }
  if (t < 64) {
    float s = 0.f;
    for (int c = 0; c < 16; ++c) s += pks[(p*16 + c)*64 + t];
    bkv[(size_t)p*5120 + 4096 + t] = f32_to_bf16(s);
  }
  for (int i = 4160 + t; i < 5120; i += 256) bkv[(size_t)p*5120 + i] = 0;
}

// ---------------- y = z * (qf @ kv^T), den fused as extra N column ----------------
__global__ __launch_bounds__(256) void y_gemm(const u16* __restrict__ qf, const u16* __restrict__ bkv,
                                              u16* __restrict__ y) {
  __shared__ __align__(16) u16 As[256*64];
  __shared__ __align__(16) u16 Bs[80*64];
  int p = blockIdx.x, rb = blockIdx.y;
  int t = threadIdx.x, wave = t >> 6, lane = t & 63;
  const u16* aslab = qf + ((size_t)p*8192 + (size_t)rb*256)*64;
  for (int i = t*8; i < 5120; i += 2048)
    *(int4*)&Bs[i] = *(const int4*)&bkv[(size_t)p*5120 + i];
  #pragma unroll
  for (int it = 0; it < 8; ++it)
    g2lds16(aslab + it*2048 + t*8, (char*)As + it*4096 + wave*1024);
  __syncthreads();
  const f32x4 vzero = {0.f,0.f,0.f,0.f};
  f32x4 acc[4][5];
  #pragma unroll
  for (int mi=0;mi<4;++mi)
    #pragma unroll
    for (int ni=0;ni<5;++ni) acc[mi][ni] = vzero;
  #pragma unroll
  for (int kk = 0; kk < 64; kk += 32) {
    bf16x8 af[4], bfr[5];
    #pragma unroll
    for (int mi=0;mi<4;++mi)
      af[mi] = *(const bf16x8*)&As[(wave*64 + mi*16 + (lane&15))*64 + kk + (lane>>4)*8];
    #pragma unroll
    for (int ni=0;ni<5;++ni)
      bfr[ni] = *(const bf16x8*)&Bs[(ni*16 + (lane&15))*64 + kk + (lane>>4)*8];
    #pragma unroll
    for (int mi=0;mi<4;++mi)
      #pragma unroll
      for (int ni=0;ni<5;++ni)
        acc[mi][ni] = __builtin_amdgcn_mfma_f32_16x16x32_bf16(af[mi], bfr[ni], acc[mi][ni], 0, 0, 0);
  }
  int b_ = p >> 4, h = p & 15;
  #pragma unroll
  for (int mi=0;mi<4;++mi) {
    #pragma unroll
    for (int r=0;r<4;++r) {
      float den = __shfl(acc[mi][4][r], lane & 48);
      float zf = 1.0f / (den + 1e-6f);
      int lq = rb*256 + wave*64 + mi*16 + ((lane>>4)<<2) + r;
      size_t rowbase = ((size_t)(b_*8192 + lq)*16 + h)*64;
      #pragma unroll
      for (int ni=0;ni<4;++ni)
        y[rowbase + ni*16 + (lane&15)] = f32_to_bf16(acc[mi][ni][r] * zf);
    }
  }
}

extern "C" void kernel_launch(void* const* d_in, const int* in_sizes, int n_in,
                              void* d_out, int out_size, void* d_ws, size_t ws_size,
                              hipStream_t stream) {
  const float* x  = (const float*)d_in[0];
  const float* Wq = (const float*)d_in[1];
  const float* bq = (const float*)d_in[2];
  const float* Wk = (const float*)d_in[3];
  const float* bk = (const float*)d_in[4];
  const float* Wv = (const float*)d_in[5];
  const float* bv = (const float*)d_in[6];
  const float* Wo = (const float*)d_in[7];
  const float* bo = (const float*)d_in[8];
  float* out = (float*)d_out;
  char* ws = (char*)d_ws;

  u16*  xb  = (u16*)(ws);                    // 64MB (reused as y later)
  u16*  WT  = (u16*)(ws + 67108864);         //  8MB
  u16*  qf  = (u16*)(ws + 75497472);         // 64MB [B][H][L][HD]
  u16*  kf  = (u16*)(ws + 142606336);        // 64MB
  u16*  vv  = (u16*)(ws + 209715200);        // 64MB
  float* pkv = (float*)(ws + 276824064);     // 16MB
  float* pks = (float*)(ws + 293601280);     // 256KB
  u16*  bkv = (u16*)(ws + 293863424);        // 640KB
  u16*  yb  = xb;

  auto kq = gemm8<0>; auto ko = gemm8<1>;
  hipFuncSetAttribute((const void*)kq, hipFuncAttributeMaxDynamicSharedMemorySize, 131072);
  hipFuncSetAttribute((const void*)ko, hipFuncAttributeMaxDynamicSharedMemorySize, 131072);

  cvt_x<<<16384, 256, 0, stream>>>(x, xb);
  cvt_wt<<<dim3(32,32,4), dim3(32,8), 0, stream>>>(Wq, Wk, Wv, Wo, WT);
  gemm8<0><<<dim3(512,3), 512, 131072, stream>>>(xb, WT, bq, bk, bv, qf, kf, vv, nullptr);
  kv_partial<<<dim3(64,16), 256, 0, stream>>>(kf, vv, pkv, pks);
  kv_reduce<<<64, 256, 0, stream>>>(pkv, pks, bkv);
  y_gemm<<<dim3(64,32), 256, 0, stream>>>(qf, bkv, yb);
  gemm8<1><<<dim3(512,1), 512, 131072, stream>>>(yb, WT, bo, nullptr, nullptr, nullptr, nullptr, nullptr, out);
}

// Round 9
// 413.608 us; speedup vs baseline: 1.5099x; 1.0672x over previous
//
#include <hip/hip_runtime.h>
#include <stdint.h>

typedef unsigned short u16;
typedef __attribute__((ext_vector_type(8))) short bf16x8;
typedef __attribute__((ext_vector_type(8))) unsigned short u16x8;
typedef __attribute__((ext_vector_type(4))) unsigned short u16x4;
typedef __attribute__((ext_vector_type(4))) float f32x4;

#define AS1 __attribute__((address_space(1)))
#define AS3 __attribute__((address_space(3)))

__device__ __forceinline__ u16 f32_to_bf16(float f) {
  unsigned int u = __builtin_bit_cast(unsigned int, f);
  u += 0x7FFFu + ((u >> 16) & 1u);
  return (u16)(u >> 16);
}
__device__ __forceinline__ float bf16_to_f32(u16 s) {
  return __builtin_bit_cast(float, (unsigned int)s << 16);
}
__device__ __forceinline__ void g2lds16(const void* g, void* l) {
  __builtin_amdgcn_global_load_lds((const AS1 void*)g, (AS3 void*)l, 16, 0, 0);
}

// ---------------- conversions ----------------
__global__ __launch_bounds__(256) void cvt_x(const float* __restrict__ x, u16* __restrict__ xb) {
  size_t i = ((size_t)blockIdx.x * 256 + threadIdx.x) * 8;
  float4 a = *(const float4*)(x + i);
  float4 b = *(const float4*)(x + i + 4);
  u16x8 o;
  o[0]=f32_to_bf16(a.x); o[1]=f32_to_bf16(a.y); o[2]=f32_to_bf16(a.z); o[3]=f32_to_bf16(a.w);
  o[4]=f32_to_bf16(b.x); o[5]=f32_to_bf16(b.y); o[6]=f32_to_bf16(b.z); o[7]=f32_to_bf16(b.w);
  *(u16x8*)(xb + i) = o;
}

// WT[z][n][k] = W_z[k][n], bf16.  4 matrices of 1024x1024.
__global__ void cvt_wt(const float* __restrict__ Wq, const float* __restrict__ Wk,
                       const float* __restrict__ Wv, const float* __restrict__ Wo,
                       u16* __restrict__ WT) {
  __shared__ float tile[32][33];
  const float* W = blockIdx.z==0 ? Wq : blockIdx.z==1 ? Wk : blockIdx.z==2 ? Wv : Wo;
  int n0 = blockIdx.x*32, k0 = blockIdx.y*32;
  int tx = threadIdx.x, ty = threadIdx.y;
  for (int r = ty; r < 32; r += 8)
    tile[r][tx] = W[(size_t)(k0+r)*1024 + n0 + tx];
  __syncthreads();
  u16* out = WT + (size_t)blockIdx.z*1024*1024;
  for (int r = ty; r < 32; r += 8)
    out[(size_t)(n0+r)*1024 + k0 + tx] = f32_to_bf16(tile[tx][r]);
}

// vvT rows 64..79: row 64 = 1.0 (ksum ones-row), rows 65..79 = 0.
__global__ __launch_bounds__(256) void init_vvT(u16* __restrict__ vvT) {
  int idx = blockIdx.x*256 + threadIdx.x;       // 1,048,576 threads x 8 elems
  int p = idx >> 14, rem = idx & 16383;
  int row = 64 + (rem >> 10), col8 = (rem & 1023) * 8;
  u16 v = (row == 64) ? (u16)0x3F80 : (u16)0;
  u16x8 o = {v,v,v,v,v,v,v,v};
  *(u16x8*)(vvT + ((size_t)p*80 + row)*8192 + col8) = o;
}

// ================= 256x256 8-phase GEMM (T1+T2+T3+T4+T5) =================
// 512 threads = 8 waves (2M x 4N). BK=64, K=1024 (16 tiles). LDS 128KB.
// Swizzle: LDS[row][slot] holds G[row][slot ^ (row&7)] (slot = 16B unit).
// Phase order (mh,nh): (0,0)->(0,1)->(1,1)->(1,0); fragments persist in regs.
// Waits: vmcnt(4) at ph0 (retires A0,B0,B1 of kt) and ph1 (retires A1) only —
// ph3's wait proved redundant by queue trace, removed (2 waits/K-tile).
// MODE 0 epilogue: z=0 -> qf[p][l][hd]; z=1 -> kfT[p][hd][s]; z=2 -> vvT[p][hd][s]
// MODE 1: f32 row-major out = acc + bo
template<int MODE>
__global__ __launch_bounds__(512) void gemm8(const u16* __restrict__ A, const u16* __restrict__ WT,
    const float* __restrict__ bq, const float* __restrict__ bk, const float* __restrict__ bv,
    u16* __restrict__ qf, u16* __restrict__ kfT, u16* __restrict__ vvT,
    float* __restrict__ fout) {
  extern __shared__ u16 lds[];
  const int z = (MODE==0) ? blockIdx.y : 3;
  const u16* Bt = WT + (size_t)z*1048576;
  int bid = blockIdx.x;
  int swz = (bid & 7)*64 + (bid >> 3);        // 512 blocks, bijective XCD swizzle
  int rb = swz >> 2, cb = swz & 3;
  const int gm0 = rb*256, gn0 = cb*256;
  const int t = threadIdx.x, w = t>>6, l = t&63;
  const int wm = w>>2, wn = w&3;
  const int lrow = l & 15, lks = l >> 4;
  const int csw = (l&7) ^ (l>>3);             // pre-swizzled source slot
  const u16* aBase = A  + (size_t)(gm0 + w*8 + (l>>3))*1024 + csw*8;
  const u16* bBase = Bt + (size_t)(gn0 + w*8 + (l>>3))*1024 + csw*8;

  f32x4 acc[2][2][4][2];
  const f32x4 vzero = {0.f,0.f,0.f,0.f};
  #pragma unroll
  for (int a0=0;a0<2;++a0)
    #pragma unroll
    for (int b0i=0;b0i<2;++b0i)
      #pragma unroll
      for (int c0=0;c0<4;++c0)
        #pragma unroll
        for (int d0=0;d0<2;++d0) acc[a0][b0i][c0][d0] = vzero;

  // prologue: stage full tile 0 into buf0
  #pragma unroll
  for (int half=0; half<2; ++half)
    #pragma unroll
    for (int j=0;j<2;++j) {
      g2lds16(aBase + (half*128 + j*64)*1024, (char*)lds + half*16384 + j*8192 + w*1024);
      g2lds16(bBase + (half*128 + j*64)*1024, (char*)lds + 65536 + half*16384 + j*8192 + w*1024);
    }
  asm volatile("s_waitcnt vmcnt(0)" ::: "memory");
  __builtin_amdgcn_s_barrier();
  asm volatile("" ::: "memory");

  for (int kt = 0; kt < 16; ++kt) {
    const int buf = kt & 1;
    const char* Ab = (const char*)lds + buf*32768;
    const char* Bb = (const char*)lds + 65536 + buf*32768;
    char* An = (char*)lds + (buf^1)*32768;
    char* Bn = (char*)lds + 65536 + (buf^1)*32768;
    const u16* aSrc = aBase + (size_t)(kt+1)*64;
    const u16* bSrc = bBase + (size_t)(kt+1)*64;
    const bool pf = (kt < 15);

    bf16x8 af[4][2];   // current mh's A fragments
    bf16x8 b0[2][2];   // nh=0 B fragments (persist ph0->ph3)
    bf16x8 b1[2][2];   // nh=1 B fragments (persist ph1->ph2)

    #define LD_A(MH)                                                         \
      _Pragma("unroll")                                                      \
      for (int mi=0;mi<4;++mi) {                                             \
        int row = (MH)*128 + wm*64 + mi*16 + lrow;                           \
        _Pragma("unroll")                                                    \
        for (int kx=0;kx<2;++kx)                                             \
          af[mi][kx] = *(const bf16x8*)(Ab + row*128 + (((kx*4+lks) ^ (row&7))<<4)); \
      }
    #define LD_B(DST,NH)                                                     \
      _Pragma("unroll")                                                      \
      for (int ni=0;ni<2;++ni) {                                             \
        int row = (NH)*128 + wn*32 + ni*16 + lrow;                           \
        _Pragma("unroll")                                                    \
        for (int kx=0;kx<2;++kx)                                             \
          DST[ni][kx] = *(const bf16x8*)(Bb + row*128 + (((kx*4+lks) ^ (row&7))<<4)); \
      }
    #define MFMA16(MH,NH,BF)                                                 \
      __builtin_amdgcn_s_setprio(1);                                         \
      _Pragma("unroll")                                                      \
      for (int mi=0;mi<4;++mi)                                               \
        _Pragma("unroll")                                                    \
        for (int ni=0;ni<2;++ni) {                                           \
          acc[MH][NH][mi][ni] = __builtin_amdgcn_mfma_f32_16x16x32_bf16(af[mi][0], BF[ni][0], acc[MH][NH][mi][ni], 0,0,0); \
          acc[MH][NH][mi][ni] = __builtin_amdgcn_mfma_f32_16x16x32_bf16(af[mi][1], BF[ni][1], acc[MH][NH][mi][ni], 0,0,0); \
        }                                                                    \
      __builtin_amdgcn_s_setprio(0);                                         \
      __builtin_amdgcn_s_barrier();                                          \
      asm volatile("" ::: "memory");

    // ---- phase 0: (mh0, nh0) ----
    LD_A(0); LD_B(b0, 0);
    if (pf) { g2lds16(aSrc, An + w*1024); g2lds16(aSrc + 64*1024, An + 8192 + w*1024); }
    if (pf) { asm volatile("s_waitcnt vmcnt(4)" ::: "memory"); }
    else    { asm volatile("s_waitcnt vmcnt(2)" ::: "memory"); }
    __builtin_amdgcn_s_barrier();
    asm volatile("" ::: "memory");
    MFMA16(0, 0, b0);

    // ---- phase 1: (mh0, nh1) ----
    LD_B(b1, 1);
    if (pf) { g2lds16(bSrc, Bn + w*1024); g2lds16(bSrc + 64*1024, Bn + 8192 + w*1024); }
    if (pf) { asm volatile("s_waitcnt vmcnt(4)" ::: "memory"); }
    else    { asm volatile("s_waitcnt vmcnt(0)" ::: "memory"); }
    __builtin_amdgcn_s_barrier();
    asm volatile("" ::: "memory");
    MFMA16(0, 1, b1);

    // ---- phase 2: (mh1, nh1) ----
    LD_A(1);
    if (pf) { g2lds16(bSrc + 128*1024, Bn + 16384 + w*1024); g2lds16(bSrc + 192*1024, Bn + 24576 + w*1024); }
    __builtin_amdgcn_s_barrier();
    asm volatile("" ::: "memory");
    MFMA16(1, 1, b1);

    // ---- phase 3: (mh1, nh0) ----  (no vmcnt: ph0/ph1 waits cover all reads)
    if (pf) { g2lds16(aSrc + 128*1024, An + 16384 + w*1024); g2lds16(aSrc + 192*1024, An + 24576 + w*1024); }
    __builtin_amdgcn_s_barrier();
    asm volatile("" ::: "memory");
    MFMA16(1, 0, b0);

    #undef LD_A
    #undef LD_B
    #undef MFMA16
  }

  // epilogue
  if (MODE == 0) {
    const float* bias = z==0 ? bq : (z==1 ? bk : bv);
    const bool feat = (z < 2);
    if (z == 0) {
      #pragma unroll
      for (int mh=0;mh<2;++mh)
        #pragma unroll
        for (int nh=0;nh<2;++nh)
          #pragma unroll
          for (int mi=0;mi<4;++mi)
            #pragma unroll
            for (int ni=0;ni<2;++ni) {
              int n = gn0 + nh*128 + wn*32 + ni*16 + lrow;
              float bn = bias[n];
              int h = n>>6, hd = n&63;
              int mbase = gm0 + mh*128 + wm*64 + mi*16 + (lks<<2);
              #pragma unroll
              for (int r=0;r<4;++r) {
                int m = mbase + r;
                float val = acc[mh][nh][mi][ni][r] + bn;
                val = val>0.f ? val+1.f : __expf(val);
                qf[((size_t)((m>>13)*16 + h)*8192 + (m&8191))*64 + hd] = f32_to_bf16(val);
              }
            }
    } else {
      // transposed: out[p][hd][s], pair stride rows = 64 (kfT) / 80 (vvT)
      u16* outp = (z==1) ? kfT : vvT;
      const size_t prow = (z==1) ? 64 : 80;
      #pragma unroll
      for (int mh=0;mh<2;++mh)
        #pragma unroll
        for (int nh=0;nh<2;++nh)
          #pragma unroll
          for (int mi=0;mi<4;++mi)
            #pragma unroll
            for (int ni=0;ni<2;++ni) {
              int n = gn0 + nh*128 + wn*32 + ni*16 + lrow;
              float bn = bias[n];
              int h = n>>6, hd = n&63;
              int mbase = gm0 + mh*128 + wm*64 + mi*16 + (lks<<2);
              int b_ = mbase >> 13, s = mbase & 8191;
              u16x4 pk;
              #pragma unroll
              for (int r=0;r<4;++r) {
                float val = acc[mh][nh][mi][ni][r] + bn;
                if (feat) val = val>0.f ? val+1.f : __expf(val);
                pk[r] = f32_to_bf16(val);
              }
              *(u16x4*)(outp + ((size_t)(b_*16 + h)*prow + hd)*8192 + s) = pk;
            }
    }
  } else {
    #pragma unroll
    for (int mh=0;mh<2;++mh)
      #pragma unroll
      for (int nh=0;nh<2;++nh)
        #pragma unroll
        for (int mi=0;mi<4;++mi)
          #pragma unroll
          for (int ni=0;ni<2;++ni) {
            int n = gn0 + nh*128 + wn*32 + ni*16 + lrow;
            float bn = bq[n];   // MODE1: bq carries bo
            int mbase = gm0 + mh*128 + wm*64 + mi*16 + (lks<<2);
            #pragma unroll
            for (int r=0;r<4;++r) {
              int m = mbase + r;
              fout[(size_t)m*1024 + n] = acc[mh][nh][mi][ni][r] + bn;
            }
          }
  }
}

// ---------------- kv via MFMA: C[m][d] = sum_s vvT[m][s]*kfT[d][s] ----------------
// per (pair, kchunk of 512): 2 sub-stages of 256. LDS 72KB (2 blocks/CU).
// 256 thr = 4 waves; wave w owns d-cols w*16..+15, all 5 m-tiles (80 rows).
// Row 64 of vvT is ones -> C row 64 = ksum. Swizzle: slot ^ (row&7), 32 slots/row.
__global__ __launch_bounds__(256) void kv_mfma(const u16* __restrict__ kfT, const u16* __restrict__ vvT,
                                               float* __restrict__ pkv) {
  __shared__ __align__(16) u16 lA[80*256];   // 40KB vvT tile
  __shared__ __align__(16) u16 lB[64*256];   // 32KB kfT tile
  const int p = blockIdx.x, c = blockIdx.y;
  const int t = threadIdx.x, w = t>>6, l = t&63;
  const int srow = t >> 5;                   // staged row within 8-row group
  const int csw = (t&31) ^ ((t>>5)&7);       // pre-swizzled source slot
  const u16* aRow = vvT + ((size_t)p*80 + srow)*8192 + (size_t)c*512 + csw*8;
  const u16* bRow = kfT + ((size_t)p*64 + srow)*8192 + (size_t)c*512 + csw*8;

  f32x4 acc5[5];
  const f32x4 vzero = {0.f,0.f,0.f,0.f};
  #pragma unroll
  for (int mi=0;mi<5;++mi) acc5[mi] = vzero;

  for (int sub = 0; sub < 2; ++sub) {
    const size_t so = (size_t)sub*256;
    #pragma unroll
    for (int i=0;i<10;++i)
      g2lds16(aRow + (size_t)i*8*8192 + so, (char*)lA + i*4096 + t*16);
    #pragma unroll
    for (int i=0;i<8;++i)
      g2lds16(bRow + (size_t)i*8*8192 + so, (char*)lB + i*4096 + t*16);
    asm volatile("s_waitcnt vmcnt(0)" ::: "memory");
    __builtin_amdgcn_s_barrier();
    asm volatile("" ::: "memory");
    #pragma unroll
    for (int ks=0;ks<8;++ks) {
      const int brow = w*16 + (l&15);
      const int slot = ks*4 + (l>>4);
      bf16x8 bfr = *(const bf16x8*)((const char*)lB + brow*512 + ((slot ^ (brow&7))<<4));
      #pragma unroll
      for (int mi=0;mi<5;++mi) {
        const int arow = mi*16 + (l&15);
        bf16x8 afr = *(const bf16x8*)((const char*)lA + arow*512 + ((slot ^ (arow&7))<<4));
        acc5[mi] = __builtin_amdgcn_mfma_f32_16x16x32_bf16(afr, bfr, acc5[mi], 0,0,0);
      }
    }
    __builtin_amdgcn_s_barrier();
    asm volatile("" ::: "memory");
  }

  float* po = pkv + ((size_t)p*16 + c)*5120;
  #pragma unroll
  for (int mi=0;mi<5;++mi)
    #pragma unroll
    for (int r=0;r<4;++r)
      po[(mi*16 + (l>>4)*4 + r)*64 + w*16 + (l&15)] = acc5[mi][r];
}

// ---------------- reduce partials -> bkv[p][80][64] bf16 ----------------
__global__ __launch_bounds__(256) void kv_reduce(const float* __restrict__ pkv, u16* __restrict__ bkv) {
  int p = blockIdx.x, t = threadIdx.x;
  for (int i = t; i < 5120; i += 256) {
    float s = 0.f;
    for (int c = 0; c < 16; ++c) s += pkv[((size_t)p*16 + c)*5120 + i];
    bkv[(size_t)p*5120 + i] = f32_to_bf16(s);
  }
}

// ---------------- y = z * (qf @ kv^T), den fused as extra N column ----------------
__global__ __launch_bounds__(256) void y_gemm(const u16* __restrict__ qf, const u16* __restrict__ bkv,
                                              u16* __restrict__ y) {
  __shared__ __align__(16) u16 As[256*64];
  __shared__ __align__(16) u16 Bs[80*64];
  int p = blockIdx.x, rb = blockIdx.y;
  int t = threadIdx.x, wave = t >> 6, lane = t & 63;
  const u16* aslab = qf + ((size_t)p*8192 + (size_t)rb*256)*64;
  for (int i = t*8; i < 5120; i += 2048)
    *(int4*)&Bs[i] = *(const int4*)&bkv[(size_t)p*5120 + i];
  #pragma unroll
  for (int it = 0; it < 8; ++it)
    g2lds16(aslab + it*2048 + t*8, (char*)As + it*4096 + wave*1024);
  __syncthreads();
  const f32x4 vzero = {0.f,0.f,0.f,0.f};
  f32x4 acc[4][5];
  #pragma unroll
  for (int mi=0;mi<4;++mi)
    #pragma unroll
    for (int ni=0;ni<5;++ni) acc[mi][ni] = vzero;
  #pragma unroll
  for (int kk = 0; kk < 64; kk += 32) {
    bf16x8 af[4], bfr[5];
    #pragma unroll
    for (int mi=0;mi<4;++mi)
      af[mi] = *(const bf16x8*)&As[(wave*64 + mi*16 + (lane&15))*64 + kk + (lane>>4)*8];
    #pragma unroll
    for (int ni=0;ni<5;++ni)
      bfr[ni] = *(const bf16x8*)&Bs[(ni*16 + (lane&15))*64 + kk + (lane>>4)*8];
    #pragma unroll
    for (int mi=0;mi<4;++mi)
      #pragma unroll
      for (int ni=0;ni<5;++ni)
        acc[mi][ni] = __builtin_amdgcn_mfma_f32_16x16x32_bf16(af[mi], bfr[ni], acc[mi][ni], 0, 0, 0);
  }
  int b_ = p >> 4, h = p & 15;
  #pragma unroll
  for (int mi=0;mi<4;++mi) {
    #pragma unroll
    for (int r=0;r<4;++r) {
      float den = __shfl(acc[mi][4][r], lane & 48);
      float zf = 1.0f / (den + 1e-6f);
      int lq = rb*256 + wave*64 + mi*16 + ((lane>>4)<<2) + r;
      size_t rowbase = ((size_t)(b_*8192 + lq)*16 + h)*64;
      #pragma unroll
      for (int ni=0;ni<4;++ni)
        y[rowbase + ni*16 + (lane&15)] = f32_to_bf16(acc[mi][ni][r] * zf);
    }
  }
}

extern "C" void kernel_launch(void* const* d_in, const int* in_sizes, int n_in,
                              void* d_out, int out_size, void* d_ws, size_t ws_size,
                              hipStream_t stream) {
  const float* x  = (const float*)d_in[0];
  const float* Wq = (const float*)d_in[1];
  const float* bq = (const float*)d_in[2];
  const float* Wk = (const float*)d_in[3];
  const float* bk = (const float*)d_in[4];
  const float* Wv = (const float*)d_in[5];
  const float* bv = (const float*)d_in[6];
  const float* Wo = (const float*)d_in[7];
  const float* bo = (const float*)d_in[8];
  float* out = (float*)d_out;
  char* ws = (char*)d_ws;

  u16*  xb  = (u16*)(ws);                    // 64MB; later aliased by pkv, then yb
  u16*  WT  = (u16*)(ws + 67108864);         //  8MB
  u16*  qf  = (u16*)(ws + 75497472);         // 64MB [64p][8192][64]
  u16*  kfT = (u16*)(ws + 142606336);        // 64MB [64p][64][8192]
  u16*  vvT = (u16*)(ws + 209715200);        // 80MB [64p][80][8192] (row64=1, 65-79=0)
  u16*  bkv = (u16*)(ws + 293601280);        // 640KB [64p][80][64]
  float* pkv = (float*)(ws);                 // 21MB, aliases xb (dead after gemm8<0>)
  u16*  yb  = xb;                            // aliases xb/pkv (written after pkv consumed)

  auto kq = gemm8<0>; auto ko = gemm8<1>;
  hipFuncSetAttribute((const void*)kq, hipFuncAttributeMaxDynamicSharedMemorySize, 131072);
  hipFuncSetAttribute((const void*)ko, hipFuncAttributeMaxDynamicSharedMemorySize, 131072);

  cvt_x<<<16384, 256, 0, stream>>>(x, xb);
  cvt_wt<<<dim3(32,32,4), dim3(32,8), 0, stream>>>(Wq, Wk, Wv, Wo, WT);
  init_vvT<<<4096, 256, 0, stream>>>(vvT);
  gemm8<0><<<dim3(512,3), 512, 131072, stream>>>(xb, WT, bq, bk, bv, qf, kfT, vvT, nullptr);
  kv_mfma<<<dim3(64,16), 256, 0, stream>>>(kfT, vvT, pkv);
  kv_reduce<<<64, 256, 0, stream>>>(pkv, bkv);
  y_gemm<<<dim3(64,32), 256, 0, stream>>>(qf, bkv, yb);
  gemm8<1><<<dim3(512,1), 512, 131072, stream>>>(yb, WT, bo, nullptr, nullptr, nullptr, nullptr, nullptr, out);
}